// Round 16
// baseline (456.620 us; speedup 1.0000x reference)
//
#include <hip/hip_runtime.h>
#include <hip/hip_bf16.h>
#include <hip/hip_fp16.h>
#include <stdint.h>

// Problem constants (setup_inputs is fixed-shape)
#define DDIM  512
#define NROWS 4096            // 8*512 query rows
#define VOCAB 50257
#define BM2 256               // gemm row-tile
#define BN 128
#define BK 64
#define NT ((VOCAB + BN - 1) / BN)   // 393 col tiles
#define NT2 ((NT + 1) / 2)           // 197 tile PAIRS (tier-A)
#define NTP (NT2 * 2)                // 394 padded tiles
#define VC2 16                       // chunks -> 16x16=256 blocks = 1/CU (R13-verified)
#define RB2 (NROWS / BM2)            // 16 row blocks
#define EB_ROWS (NTP * BN)           // 50432 (padded vocab rows)
#define TW16 (NTP * 32)              // 12608 4-col slots per row (f16 tm)
#define TAU16 0.04f                  // margin: mfma chain (~0.01) + 2x f16 rnd (0.004)
#define TAU1  0.02f                  // tier-B margin (f32 tm, R6-verified)
#define LISTCAP (1 << 18)

typedef short bf16x8 __attribute__((ext_vector_type(8)));
typedef float f32x4  __attribute__((ext_vector_type(4)));

// order-preserving encode of fp32 into uint32 (for atomicMax)
__device__ __forceinline__ unsigned int enc_f32(float f) {
    unsigned int u = __float_as_uint(f);
    return (u & 0x80000000u) ? ~u : (u | 0x80000000u);
}
__device__ __forceinline__ float dec_f32(unsigned int e) {
    unsigned int u = (e & 0x80000000u) ? (e & 0x7fffffffu) : ~e;
    return __uint_as_float(u);
}
__device__ __forceinline__ unsigned short bf16_rne(float f) {
    unsigned int u = __float_as_uint(f);
    u += 0x7fffu + ((u >> 16) & 1u);
    return (unsigned short)(u >> 16);
}
__device__ __forceinline__ void gload16(const short* g, short* l) {
    __builtin_amdgcn_global_load_lds(
        (const __attribute__((address_space(1))) void*)g,
        (__attribute__((address_space(3))) void*)l, 16, 0, 0);
}
__device__ __forceinline__ uint4 pack8(float4 a, float4 b) {
    uint4 wv;
    wv.x = ((unsigned)bf16_rne(a.y) << 16) | bf16_rne(a.x);
    wv.y = ((unsigned)bf16_rne(a.w) << 16) | bf16_rne(a.z);
    wv.z = ((unsigned)bf16_rne(b.y) << 16) | bf16_rne(b.x);
    wv.w = ((unsigned)bf16_rne(b.w) << 16) | bf16_rne(b.z);
    return wv;
}

// ============================ shared prep ============================

// X fp32 -> bf16 (4096x512); also zeroes candidate counter
__global__ void k_conv_x(const float* __restrict__ X, short* __restrict__ Xb,
                         unsigned* __restrict__ cnt) {
    int i = blockIdx.x * 256 + threadIdx.x;        // one 8-elem group per thread
    if (i == 0) *cnt = 0u;
    const float4* p = (const float4*)X + (size_t)i * 2;
    float4 a = p[0], b = p[1];
    *(uint4*)(Xb + (size_t)i * 8) = pack8(a, b);
}

// E fp32 -> bf16 (padded to EB_ROWS, zeros beyond VOCAB) + inv norms
__global__ void k_conv_e(const float* __restrict__ E, short* __restrict__ Eb,
                         float* __restrict__ invn) {
    int lane = threadIdx.x & 63;
    int wid  = blockIdx.x * 4 + (threadIdx.x >> 6);
    int nw   = gridDim.x * 4;
    for (int r = wid; r < EB_ROWS; r += nw) {
        if (r < VOCAB) {
            const float4* p = (const float4*)(E + (size_t)r * DDIM) + lane * 2;
            float4 a = p[0], b = p[1];
            float s = a.x*a.x + a.y*a.y + a.z*a.z + a.w*a.w
                    + b.x*b.x + b.y*b.y + b.z*b.z + b.w*b.w;
            #pragma unroll
            for (int off = 32; off; off >>= 1) s += __shfl_xor(s, off, 64);
            *(uint4*)(Eb + (size_t)r * DDIM + lane * 8) = pack8(a, b);
            if (lane == 0) invn[r] = 1.0f / fmaxf(sqrtf(s), 1e-12f);
        } else {
            uint4 z; z.x = z.y = z.z = z.w = 0u;
            *(uint4*)(Eb + (size_t)r * DDIM + lane * 8) = z;
            if (lane == 0) invn[r] = 0.0f;
        }
    }
}

// ======= tier A: dual-tile A-reuse, BK=64, 2-buf __syncthreads pipeline =======

// R9/R13-verified BK=64 staging (128B per row per step -> full DRAM lines;
// R15's BK=32 halved this and doubled FETCH). Pre-swizzled source, linear dest.
__device__ __forceinline__ void stA(const short* Xb, short* Ab,
                                    int row0, int k0, int tid) {
    #pragma unroll
    for (int i = 0; i < 4; ++i) {
        int c = tid + i * 512;
        int r = c >> 3, g = c & 7;
        int gs = (g ^ (r & 7)) * 8;
        gload16(Xb + (size_t)(row0 + r) * DDIM + k0 + gs, Ab + c * 8);
    }
}
__device__ __forceinline__ void stB(const short* Eb, short* Bb,
                                    int v0, int k0, int tid) {
    #pragma unroll
    for (int i = 0; i < 2; ++i) {
        int c = tid + i * 512;
        int r = c >> 3, g = c & 7;
        int gs = (g ^ (r & 7)) * 8;
        gload16(Eb + (size_t)(v0 + r) * DDIM + k0 + gs, Bb + c * 8);
    }
}

// Block owns PAIRS of adjacent 128-col tiles sharing one A tile: per K-step a
// wave reads av[4] once per ks-slice, feeds both tiles' bv (24 reads / 64 MFMA
// = 0.375/MFMA vs R13's 0.5 — DS pipe was the R13/R14 binder). Sync = R10's
// verified dbuf pattern: stage next-K into buf^1 BEFORE compute, ONE
// __syncthreads per step; its vmcnt(0) drain hits loads issued ~2500cy earlier
// (>> HBM latency) so it is near-free (R10's flaw was a too-short compute).
__global__ __launch_bounds__(512)
void k_gemm_fast16(const short* __restrict__ Xb, const short* __restrict__ Eb,
                   const float* __restrict__ invn, unsigned short* __restrict__ tm)
{
    extern __shared__ __align__(16) short smem[];
    short* As = smem;                            // 2 x BM2*BK (2 x 32 KB)
    short* Bs = smem + 2 * BM2 * BK;             // 2 x 2 x BN*BK (2 x 32 KB)

    const int tid  = threadIdx.x;
    const int lane = tid & 63;
    const int w    = tid >> 6;         // wave 0..7
    const int wm   = w >> 1;           // 0..3 (64-row strip)
    const int wn   = w & 1;            // 0..1 (64-col half)
    const int row0 = blockIdx.x * BM2;
    const int l15  = lane & 15, lhi = lane >> 4;

    for (int p = blockIdx.y; p < NT2; p += VC2) {
        const int t0 = 2 * p;
        const int v0 = t0 * BN, v1 = v0 + BN;
        f32x4 acc[2][4][4];
        #pragma unroll
        for (int j = 0; j < 2; ++j)
            #pragma unroll
            for (int m = 0; m < 4; ++m)
                #pragma unroll
                for (int n = 0; n < 4; ++n)
                    acc[j][m][n] = 0.0f;

        stA(Xb, As, row0, 0, tid);
        stB(Eb, Bs, v0, 0, tid);
        stB(Eb, Bs + BN * BK, v1, 0, tid);
        __syncthreads();                         // buf0 staged (vmcnt drained)

        #pragma unroll
        for (int kt = 0; kt < DDIM / BK; ++kt) {          // 8 K-steps
            const int cur = kt & 1;
            if (kt + 1 < DDIM / BK) {                     // issue K(kt+1)
                short* An = As + (cur ^ 1) * (BM2 * BK);
                short* Bn = Bs + (cur ^ 1) * (2 * BN * BK);
                stA(Xb, An, row0, (kt + 1) * BK, tid);
                stB(Eb, Bn, v0, (kt + 1) * BK, tid);
                stB(Eb, Bn + BN * BK, v1, (kt + 1) * BK, tid);
            }

            const short* Ac = As + cur * (BM2 * BK);
            const short* B0 = Bs + cur * (2 * BN * BK);
            const short* B1 = B0 + BN * BK;
            __builtin_amdgcn_s_setprio(1);
            #pragma unroll
            for (int ks = 0; ks < 2; ++ks) {
                bf16x8 av[4], bv0[4], bv1[4];
                #pragma unroll
                for (int m = 0; m < 4; ++m) {
                    int r  = wm * 64 + m * 16 + l15;
                    int ke = (ks * 32 + lhi * 8) ^ ((r & 7) << 3);
                    av[m] = *(const bf16x8*)(Ac + r * BK + ke);
                }
                #pragma unroll
                for (int n = 0; n < 4; ++n) {
                    int c  = wn * 64 + n * 16 + l15;
                    int ke = (ks * 32 + lhi * 8) ^ ((c & 7) << 3);
                    bv0[n] = *(const bf16x8*)(B0 + c * BK + ke);
                    bv1[n] = *(const bf16x8*)(B1 + c * BK + ke);
                }
                #pragma unroll
                for (int m = 0; m < 4; ++m)
                    #pragma unroll
                    for (int n = 0; n < 4; ++n) {
                        acc[0][m][n] = __builtin_amdgcn_mfma_f32_16x16x32_bf16(
                            av[m], bv0[n], acc[0][m][n], 0, 0, 0);
                        acc[1][m][n] = __builtin_amdgcn_mfma_f32_16x16x32_bf16(
                            av[m], bv1[n], acc[1][m][n], 0, 0, 0);
                    }
            }
            __builtin_amdgcn_s_setprio(0);
            __syncthreads();   // K(kt+1) landed; all readers done with cur
        }

        // shuffle-free epilogue (R15-verified), once per tile of the pair.
        // col(n) = vj + wn*64 + n*16 + l15; row(m,q) = row0 + wm*64 + m*16 + lhi*4 + q
        #pragma unroll
        for (int j = 0; j < 2; ++j) {
            const int vj = v0 + j * BN;
            float inv[4];
            #pragma unroll
            for (int n = 0; n < 4; ++n) inv[n] = invn[vj + wn * 64 + n * 16 + l15];
            const int slotbase = (t0 + j) * 32 + wn * 16 + l15;
            #pragma unroll
            for (int m = 0; m < 4; ++m) {
                #pragma unroll
                for (int q = 0; q < 4; ++q) {
                    float s = fmaxf(
                        fmaxf(acc[j][m][0][q] * inv[0], acc[j][m][1][q] * inv[1]),
                        fmaxf(acc[j][m][2][q] * inv[2], acc[j][m][3][q] * inv[3]));
                    int row = row0 + wm * 64 + m * 16 + lhi * 4 + q;
                    tm[(size_t)row * TW16 + slotbase] = __half_as_ushort(__float2half(s));
                }
            }
        }
        // no extra barrier: next pair's stage targets buf0, whose readers all
        // passed the kt=6/7 barriers; the post-stage __syncthreads drains vmcnt.
    }
}

// one wave per row: rowmax over 12608 f16 slots, append candidates; inits keys
// list entry = (row << 14) | slot
__global__ void k_select16(const unsigned short* __restrict__ tm,
                           unsigned* __restrict__ list, unsigned* __restrict__ cnt,
                           unsigned long long* __restrict__ keys) {
    int row  = blockIdx.x * 4 + (threadIdx.x >> 6);
    int lane = threadIdx.x & 63;
    if (lane == 0) keys[row] = 0ull;
    const unsigned short* p = tm + (size_t)row * TW16;
    float m = -INFINITY;
    for (int c = lane; c < TW16 / 8; c += 64) {
        bf16x8 v = *(const bf16x8*)(p + c * 8);
        #pragma unroll
        for (int k = 0; k < 8; ++k)
            m = fmaxf(m, __half2float(__ushort_as_half((unsigned short)v[k])));
    }
    #pragma unroll
    for (int off = 32; off; off >>= 1) m = fmaxf(m, __shfl_xor(m, off, 64));
    float th = m - TAU16;
    for (int c = lane; c < TW16 / 8; c += 64) {
        bf16x8 v = *(const bf16x8*)(p + c * 8);
        #pragma unroll
        for (int k = 0; k < 8; ++k) {
            if (__half2float(__ushort_as_half((unsigned short)v[k])) >= th) {
                unsigned slot = atomicAdd(cnt, 1u);
                if (slot < LISTCAP)
                    list[slot] = ((unsigned)row << 14) | (unsigned)(c * 8 + k);
            }
        }
    }
}

// exact fp64 rescore of one 4-col slot group per wave.
// slot -> t = slot>>5, wn = (slot>>4)&1, l15 = slot&15; cols = t*128+wn*64+n*16+l15
__global__ __launch_bounds__(256)
void k_rescore4(const float* __restrict__ X, const float* __restrict__ E,
                const float* __restrict__ invn,
                const unsigned* __restrict__ list, const unsigned* __restrict__ cnt,
                unsigned long long* __restrict__ keys) {
    unsigned n = *cnt; if (n > LISTCAP) n = LISTCAP;
    int lane = (int)threadIdx.x & 63;
    int nn   = lane >> 4;              // which of the 4 cols
    int part = lane & 15;              // 16-way split of the dot product
    unsigned wv = blockIdx.x * 4 + ((unsigned)threadIdx.x >> 6);
    unsigned nw = gridDim.x * 4;
    for (unsigned ci = wv; ci < n; ci += nw) {
        unsigned e = list[ci];
        int row  = (int)(e >> 14);
        int slot = (int)(e & 16383u);
        int col  = (slot >> 5) * 128 + ((slot >> 4) & 1) * 64 + nn * 16 + (slot & 15);
        if (col < VOCAB) {
            const float4* xp = (const float4*)(X + (size_t)row * DDIM + part * 32);
            const float4* ep = (const float4*)(E + (size_t)col * DDIM + part * 32);
            double s = 0.0;
            #pragma unroll
            for (int d = 0; d < 8; ++d) {
                float4 a = xp[d], b = ep[d];
                s = fma((double)a.x, (double)b.x, s);
                s = fma((double)a.y, (double)b.y, s);
                s = fma((double)a.z, (double)b.z, s);
                s = fma((double)a.w, (double)b.w, s);
            }
            s += __shfl_xor(s, 1, 64);
            s += __shfl_xor(s, 2, 64);
            s += __shfl_xor(s, 4, 64);
            s += __shfl_xor(s, 8, 64);
            if (part == 0) {
                float fs = (float)(s * (double)invn[col]);
                unsigned long long key = ((unsigned long long)enc_f32(fs) << 32)
                                       | (unsigned long long)(0xffffffffu - (unsigned)col);
                atomicMax(keys + row, key);
            }
        }
    }
}

__global__ void k_final(const unsigned long long* __restrict__ keys,
                        int* __restrict__ out) {
    int i = blockIdx.x * 256 + threadIdx.x;
    if (i < NROWS)
        out[i] = (int)(0xffffffffu - (unsigned int)(keys[i] & 0xffffffffull));
}

// ==================== tier B: R6-verified f32 half-tile path ====================

__global__ __launch_bounds__(512)
void k_gemm_fast1(const short* __restrict__ Xb, const short* __restrict__ Eb,
                  const float* __restrict__ invn, float* __restrict__ tm)
{
    constexpr int TW = NT * 2;
    __shared__ __align__(16) short Ab[BM2 * BK];
    __shared__ __align__(16) short Bb[BN  * BK];

    const int tid  = threadIdx.x;
    const int lane = tid & 63;
    const int w    = tid >> 6;
    const int wm   = w >> 1;
    const int wn   = w & 1;
    const int row0 = blockIdx.x * BM2;
    const int l15  = lane & 15, lhi = lane >> 4;

    for (int t = blockIdx.y; t < NT; t += VC2) {
        const int v0 = t * BN;
        f32x4 acc[4][4];
        #pragma unroll
        for (int m = 0; m < 4; ++m)
            #pragma unroll
            for (int n = 0; n < 4; ++n)
                acc[m][n] = 0.0f;

        for (int kt = 0; kt < DDIM / BK; ++kt) {
            const int k0 = kt * BK;
            #pragma unroll
            for (int i = 0; i < 4; ++i) {
                int c = tid + i * 512;
                int r = c >> 3, g = c & 7;
                int gs = (g ^ (r & 7)) * 8;
                gload16(Xb + (size_t)(row0 + r) * DDIM + k0 + gs, Ab + c * 8);
            }
            #pragma unroll
            for (int i = 0; i < 2; ++i) {
                int c = tid + i * 512;
                int r = c >> 3, g = c & 7;
                int gs = (g ^ (r & 7)) * 8;
                gload16(Eb + (size_t)(v0 + r) * DDIM + k0 + gs, Bb + c * 8);
            }
            __syncthreads();
            #pragma unroll
            for (int ks = 0; ks < 2; ++ks) {
                bf16x8 av[4], bv[4];
                #pragma unroll
                for (int m = 0; m < 4; ++m) {
                    int r  = wm * 64 + m * 16 + l15;
                    int ke = (ks * 32 + lhi * 8) ^ ((r & 7) << 3);
                    av[m] = *(const bf16x8*)(Ab + r * BK + ke);
                }
                #pragma unroll
                for (int n = 0; n < 4; ++n) {
                    int c  = wn * 64 + n * 16 + l15;
                    int ke = (ks * 32 + lhi * 8) ^ ((c & 7) << 3);
                    bv[n] = *(const bf16x8*)(Bb + c * BK + ke);
                }
                #pragma unroll
                for (int m = 0; m < 4; ++m)
                    #pragma unroll
                    for (int n = 0; n < 4; ++n)
                        acc[m][n] = __builtin_amdgcn_mfma_f32_16x16x32_bf16(
                            av[m], bv[n], acc[m][n], 0, 0, 0);
            }
            __syncthreads();
        }

        float inv[4];
        #pragma unroll
        for (int n = 0; n < 4; ++n) inv[n] = invn[v0 + wn * 64 + n * 16 + l15];
        #pragma unroll
        for (int m = 0; m < 4; ++m) {
            #pragma unroll
            for (int j = 0; j < 4; ++j) {
                float v = fmaxf(fmaxf(acc[m][0][j] * inv[0], acc[m][1][j] * inv[1]),
                                fmaxf(acc[m][2][j] * inv[2], acc[m][3][j] * inv[3]));
                #pragma unroll
                for (int off = 1; off < 16; off <<= 1)
                    v = fmaxf(v, __shfl_xor(v, off, 64));
                if (l15 == 0) {
                    int row = row0 + wm * 64 + m * 16 + lhi * 4 + j;
                    tm[(size_t)row * TW + t * 2 + wn] = v;
                }
            }
        }
    }
}

__global__ void k_select1(const float* __restrict__ tm,
                          unsigned* __restrict__ list, unsigned* __restrict__ cnt,
                          unsigned long long* __restrict__ keys) {
    constexpr int TW = NT * 2;
    int row  = blockIdx.x * 4 + (threadIdx.x >> 6);
    int lane = threadIdx.x & 63;
    if (lane == 0) keys[row] = 0ull;
    const float* p = tm + (size_t)row * TW;
    float m = -INFINITY;
    for (int i = lane; i < TW; i += 64) m = fmaxf(m, p[i]);
    #pragma unroll
    for (int off = 32; off; off >>= 1) m = fmaxf(m, __shfl_xor(m, off, 64));
    float th = m - TAU1;
    for (int i = lane; i < TW; i += 64) {
        if (p[i] >= th) {
            unsigned slot = atomicAdd(cnt, 1u);
            if (slot < LISTCAP) list[slot] = ((unsigned)row << 14) | (unsigned)i;
        }
    }
}

__global__ __launch_bounds__(256)
void k_rescore64(const float* __restrict__ X, const float* __restrict__ E,
                 const float* __restrict__ invn,
                 const unsigned* __restrict__ list, const unsigned* __restrict__ cnt,
                 unsigned long long* __restrict__ keys) {
    unsigned n = *cnt; if (n > LISTCAP) n = LISTCAP;
    for (unsigned ci = blockIdx.x; ci < n; ci += gridDim.x) {
        unsigned e = list[ci];
        int row = (int)(e >> 14);
        int idx = (int)(e & 16383u);
        int v0  = (idx >> 1) * BN + (idx & 1) * 64;
        int col  = v0 + ((int)threadIdx.x >> 2);
        int part = (int)threadIdx.x & 3;
        if (col < VOCAB) {
            const float4* xp = (const float4*)(X + (size_t)row * DDIM + part * 128);
            const float4* ep = (const float4*)(E + (size_t)col * DDIM + part * 128);
            double s = 0.0;
            #pragma unroll 8
            for (int d = 0; d < 32; ++d) {
                float4 a = xp[d], b = ep[d];
                s = fma((double)a.x, (double)b.x, s);
                s = fma((double)a.y, (double)b.y, s);
                s = fma((double)a.z, (double)b.z, s);
                s = fma((double)a.w, (double)b.w, s);
            }
            s += __shfl_xor(s, 1, 64);
            s += __shfl_xor(s, 2, 64);
            if (part == 0) {
                float fs = (float)(s * (double)invn[col]);
                unsigned long long key = ((unsigned long long)enc_f32(fs) << 32)
                                       | (unsigned long long)(0xffffffffu - (unsigned)col);
                atomicMax(keys + row, key);
            }
        }
    }
}

// ===================== fallback path (round-1, verified) =====================

#define BM 128
#define VC 33

__global__ void k_init_fb(unsigned int* rowmax, unsigned long long* keys) {
    int i = blockIdx.x * 256 + threadIdx.x;
    if (i < NROWS) { rowmax[i] = 0u; keys[i] = 0ull; }
}

__global__ void k_enorm(const float* __restrict__ E, float* __restrict__ invn) {
    int lane = threadIdx.x & 63;
    int wid  = blockIdx.x * 4 + (threadIdx.x >> 6);
    int nw   = gridDim.x * 4;
    for (int r = wid; r < VOCAB; r += nw) {
        const float4* p = (const float4*)(E + (size_t)r * DDIM);
        float4 a = p[lane];
        float4 b = p[lane + 64];
        float s = a.x*a.x + a.y*a.y + a.z*a.z + a.w*a.w
                + b.x*b.x + b.y*b.y + b.z*b.z + b.w*b.w;
        #pragma unroll
        for (int off = 32; off; off >>= 1) s += __shfl_xor(s, off, 64);
        if (lane == 0) invn[r] = 1.0f / fmaxf(sqrtf(s), 1e-12f);
    }
}

__device__ __noinline__ void rescore1(const float* __restrict__ X,
                                      const float* __restrict__ E,
                                      float iv, int row, int col,
                                      unsigned long long* keys) {
    const float4* xp = (const float4*)(X + (size_t)row * DDIM);
    const float4* ep = (const float4*)(E + (size_t)col * DDIM);
    double a0 = 0.0, a1 = 0.0, a2 = 0.0, a3 = 0.0;
    for (int d = 0; d < DDIM / 4; ++d) {
        float4 x4 = xp[d], e4 = ep[d];
        a0 = fma((double)x4.x, (double)e4.x, a0);
        a1 = fma((double)x4.y, (double)e4.y, a1);
        a2 = fma((double)x4.z, (double)e4.z, a2);
        a3 = fma((double)x4.w, (double)e4.w, a3);
    }
    float fs = (float)((((a0 + a1) + (a2 + a3))) * (double)iv);
    unsigned long long key = ((unsigned long long)enc_f32(fs) << 32)
                           | (unsigned long long)(0xffffffffu - (unsigned int)col);
    atomicMax(keys + row, key);
}

template <int PASS>
__global__ __launch_bounds__(256, 2)
void k_gemm_fb(const float* __restrict__ X, const float* __restrict__ E,
               const float* __restrict__ invn,
               unsigned int* __restrict__ rowmax,
               unsigned long long* __restrict__ keys)
{
    __shared__ __align__(16) short Abuf[BM * BK];
    __shared__ __align__(16) short Bbuf[BN * BK];

    const int tid  = threadIdx.x;
    const int lane = tid & 63;
    const int w    = tid >> 6;
    const int wm   = w >> 1, wn = w & 1;
    const int row0 = blockIdx.y * BM;
    const int l15  = lane & 15, lhi = lane >> 4;

    float rmax[4][4];
    float thr[4][4];
    #pragma unroll
    for (int m = 0; m < 4; ++m)
        #pragma unroll
        for (int j = 0; j < 4; ++j) {
            rmax[m][j] = -INFINITY;
            if (PASS == 2) {
                int row = row0 + wm * 64 + m * 16 + lhi * 4 + j;
                thr[m][j] = dec_f32(rowmax[row]) - TAU1;
            }
        }

    for (int t = blockIdx.x; t < NT; t += VC) {
        const int v0 = t * BN;
        f32x4 acc[4][4];
        #pragma unroll
        for (int m = 0; m < 4; ++m)
            #pragma unroll
            for (int n = 0; n < 4; ++n)
                acc[m][n] = 0.0f;

        for (int kt = 0; kt < DDIM / BK; ++kt) {
            const int k0 = kt * BK;
            #pragma unroll
            for (int i = 0; i < 4; ++i) {
                int f  = tid + i * 256;
                int r  = f >> 3;
                int ks = (f & 7) * 8;
                const float* src = X + (size_t)(row0 + r) * DDIM + k0 + ks;
                float4 aa = *(const float4*)src;
                float4 bb = *(const float4*)(src + 4);
                *(uint4*)(Abuf + r * BK + (ks ^ ((r & 7) << 3))) = pack8(aa, bb);
            }
            #pragma unroll
            for (int i = 0; i < 4; ++i) {
                int f  = tid + i * 256;
                int r  = f >> 3;
                int ks = (f & 7) * 8;
                float4 aa = {0.f,0.f,0.f,0.f}, bb = {0.f,0.f,0.f,0.f};
                if (v0 + r < VOCAB) {
                    const float* src = E + (size_t)(v0 + r) * DDIM + k0 + ks;
                    aa = *(const float4*)src;
                    bb = *(const float4*)(src + 4);
                }
                *(uint4*)(Bbuf + r * BK + (ks ^ ((r & 7) << 3))) = pack8(aa, bb);
            }
            __syncthreads();
            #pragma unroll
            for (int ks = 0; ks < 2; ++ks) {
                bf16x8 av[4], bv[4];
                #pragma unroll
                for (int m = 0; m < 4; ++m) {
                    int r  = wm * 64 + m * 16 + l15;
                    int ke = (ks * 32 + lhi * 8) ^ ((r & 7) << 3);
                    av[m] = *(const bf16x8*)(Abuf + r * BK + ke);
                }
                #pragma unroll
                for (int n = 0; n < 4; ++n) {
                    int c  = wn * 64 + n * 16 + l15;
                    int ke = (ks * 32 + lhi * 8) ^ ((c & 7) << 3);
                    bv[n] = *(const bf16x8*)(Bbuf + c * BK + ke);
                }
                #pragma unroll
                for (int m = 0; m < 4; ++m)
                    #pragma unroll
                    for (int n = 0; n < 4; ++n)
                        acc[m][n] = __builtin_amdgcn_mfma_f32_16x16x32_bf16(
                            av[m], bv[n], acc[m][n], 0, 0, 0);
            }
            __syncthreads();
        }

        float inv[4]; int colv[4];
        #pragma unroll
        for (int n = 0; n < 4; ++n) {
            int c = v0 + wn * 64 + n * 16 + l15;
            colv[n] = c;
            inv[n] = (c < VOCAB) ? invn[c] : 0.0f;
        }
        if (PASS == 1) {
            #pragma unroll
            for (int m = 0; m < 4; ++m)
                #pragma unroll
                for (int n = 0; n < 4; ++n)
                    if (colv[n] < VOCAB) {
                        #pragma unroll
                        for (int j = 0; j < 4; ++j)
                            rmax[m][j] = fmaxf(rmax[m][j], acc[m][n][j] * inv[n]);
                    }
        } else {
            #pragma unroll
            for (int m = 0; m < 4; ++m)
                #pragma unroll
                for (int n = 0; n < 4; ++n)
                    if (colv[n] < VOCAB) {
                        #pragma unroll
                        for (int j = 0; j < 4; ++j) {
                            float sc = acc[m][n][j] * inv[n];
                            if (sc >= thr[m][j]) {
                                int row = row0 + wm * 64 + m * 16 + lhi * 4 + j;
                                rescore1(X, E, inv[n], row, colv[n], keys);
                            }
                        }
                    }
        }
    }

    if (PASS == 1) {
        #pragma unroll
        for (int m = 0; m < 4; ++m)
            #pragma unroll
            for (int j = 0; j < 4; ++j) {
                float v = rmax[m][j];
                #pragma unroll
                for (int off = 1; off < 16; off <<= 1)
                    v = fmaxf(v, __shfl_xor(v, off, 64));
                if (l15 == 0) {
                    int row = row0 + wm * 64 + m * 16 + lhi * 4 + j;
                    atomicMax(rowmax + row, enc_f32(v));
                }
            }
    }
}

// =============================== launch ===============================

extern "C" void kernel_launch(void* const* d_in, const int* in_sizes, int n_in,
                              void* d_out, int out_size, void* d_ws, size_t ws_size,
                              hipStream_t stream) {
    const float* X = (const float*)d_in[0];   // (4096, 512)
    const float* E = (const float*)d_in[1];   // (50257, 512)
    int* out = (int*)d_out;                   // (4096,) int32
    char* ws = (char*)d_ws;

    const size_t sz_Eb    = (size_t)EB_ROWS * DDIM * 2;          // 51,642,368
    const size_t sz_Xb    = (size_t)NROWS * DDIM * 2;            //  4,194,304
    const size_t sz_invn  = (size_t)EB_ROWS * 4;                 //    201,728
    const size_t sz_keys  = (size_t)NROWS * 8;
    const size_t sz_list  = (size_t)LISTCAP * 4;
    const size_t fixed    = sz_Eb + sz_Xb + sz_invn + sz_keys + sz_list + 256;
    const size_t sz_tm16  = (size_t)NROWS * TW16 * 2;            // 103,284,736
    const size_t sz_tm1   = (size_t)NROWS * (NT * 2) * 4;        // 12,877,824

    int tier = 0;
    if (ws_size >= fixed + sz_tm16)     tier = 16;
    else if (ws_size >= fixed + sz_tm1) tier = 1;

    if (tier) {
        const size_t sz_tm = (tier == 16) ? sz_tm16 : sz_tm1;
        short* Eb   = (short*)(ws);
        short* Xb   = (short*)(ws + sz_Eb);
        float* invn = (float*)(ws + sz_Eb + sz_Xb);
        char*  tmb  = ws + sz_Eb + sz_Xb + sz_invn;
        unsigned long long* keys = (unsigned long long*)(tmb + sz_tm);
        unsigned* list = (unsigned*)((char*)keys + sz_keys);
        unsigned* cnt  = (unsigned*)((char*)list + sz_list);

        k_conv_x<<<(NROWS * DDIM / 8) / 256, 256, 0, stream>>>(X, Xb, cnt);
        k_conv_e<<<2048, 256, 0, stream>>>(E, Eb, invn);
        dim3 g(RB2, VC2);
        if (tier == 16) {
            const size_t smem = (size_t)2 * (BM2 * BK + 2 * BN * BK) * sizeof(short); // 128 KB
            k_gemm_fast16<<<g, 512, smem, stream>>>(Xb, Eb, invn, (unsigned short*)tmb);
            k_select16<<<NROWS / 4, 256, 0, stream>>>((unsigned short*)tmb, list, cnt, keys);
            k_rescore4<<<2048, 256, 0, stream>>>(X, E, invn, list, cnt, keys);
        } else {
            k_gemm_fast1<<<g, 512, 0, stream>>>(Xb, Eb, invn, (float*)tmb);
            k_select1<<<NROWS / 4, 256, 0, stream>>>((float*)tmb, list, cnt, keys);
            k_rescore64<<<2048, 256, 0, stream>>>(X, E, invn, list, cnt, keys);
        }
        k_final<<<(NROWS + 255) / 256, 256, 0, stream>>>(keys, out);
    } else {
        // fallback: round-1 verified two-pass path (small ws)
        float* invn = (float*)ws;
        size_t off0 = ((size_t)VOCAB * 4 + 255) & ~(size_t)255;
        unsigned int* rowmax = (unsigned int*)(ws + off0);
        size_t off1 = off0 + (((size_t)NROWS * 4 + 255) & ~(size_t)255);
        unsigned long long* keys = (unsigned long long*)(ws + off1);

        k_init_fb<<<(NROWS + 255) / 256, 256, 0, stream>>>(rowmax, keys);
        k_enorm<<<1024, 256, 0, stream>>>(E, invn);
        dim3 g(VC, NROWS / BM);
        k_gemm_fb<1><<<g, 256, 0, stream>>>(X, E, invn, rowmax, keys);
        k_gemm_fb<2><<<g, 256, 0, stream>>>(X, E, invn, rowmax, keys);
        k_final<<<(NROWS + 255) / 256, 256, 0, stream>>>(keys, out);
    }
}

// Round 17
// 455.700 us; speedup vs baseline: 1.0020x; 1.0020x over previous
//
#include <hip/hip_runtime.h>
#include <hip/hip_bf16.h>
#include <hip/hip_fp16.h>
#include <stdint.h>

// Problem constants (setup_inputs is fixed-shape)
#define DDIM  512
#define NROWS 4096            // 8*512 query rows
#define VOCAB 50257
#define BM2 256               // gemm row-tile
#define BN 128
#define BK 64
#define NT ((VOCAB + BN - 1) / BN)   // 393 col tiles
#define NT2 ((NT + 1) / 2)           // 197 tile PAIRS (tier-A)
#define NTP (NT2 * 2)                // 394 padded tiles
#define VC2 16                       // chunks -> 16x16=256 blocks = 1/CU (R13-verified)
#define RB2 (NROWS / BM2)            // 16 row blocks
#define EB_ROWS (NTP * BN)           // 50432 (padded vocab rows)
#define TW16 (NTP * 32)              // 12608 4-col slots per row (f16 tm)
#define TAU16 0.04f                  // margin: mfma chain (~0.01) + 2x f16 rnd (0.004)
#define TAU1  0.02f                  // tier-B margin (f32 tm, R6-verified)
#define LISTCAP (1 << 18)

typedef short bf16x8 __attribute__((ext_vector_type(8)));
typedef float f32x4  __attribute__((ext_vector_type(4)));

// order-preserving encode of fp32 into uint32 (for atomicMax)
__device__ __forceinline__ unsigned int enc_f32(float f) {
    unsigned int u = __float_as_uint(f);
    return (u & 0x80000000u) ? ~u : (u | 0x80000000u);
}
__device__ __forceinline__ float dec_f32(unsigned int e) {
    unsigned int u = (e & 0x80000000u) ? (e & 0x7fffffffu) : ~e;
    return __uint_as_float(u);
}
__device__ __forceinline__ unsigned short bf16_rne(float f) {
    unsigned int u = __float_as_uint(f);
    u += 0x7fffu + ((u >> 16) & 1u);
    return (unsigned short)(u >> 16);
}
__device__ __forceinline__ void gload16(const short* g, short* l) {
    __builtin_amdgcn_global_load_lds(
        (const __attribute__((address_space(1))) void*)g,
        (__attribute__((address_space(3))) void*)l, 16, 0, 0);
}
__device__ __forceinline__ uint4 pack8(float4 a, float4 b) {
    uint4 wv;
    wv.x = ((unsigned)bf16_rne(a.y) << 16) | bf16_rne(a.x);
    wv.y = ((unsigned)bf16_rne(a.w) << 16) | bf16_rne(a.z);
    wv.z = ((unsigned)bf16_rne(b.y) << 16) | bf16_rne(b.x);
    wv.w = ((unsigned)bf16_rne(b.w) << 16) | bf16_rne(b.z);
    return wv;
}

// ============================ shared prep ============================

// X fp32 -> bf16 (4096x512); also zeroes candidate counter
__global__ void k_conv_x(const float* __restrict__ X, short* __restrict__ Xb,
                         unsigned* __restrict__ cnt) {
    int i = blockIdx.x * 256 + threadIdx.x;        // one 8-elem group per thread
    if (i == 0) *cnt = 0u;
    const float4* p = (const float4*)X + (size_t)i * 2;
    float4 a = p[0], b = p[1];
    *(uint4*)(Xb + (size_t)i * 8) = pack8(a, b);
}

// E fp32 -> bf16 (padded to EB_ROWS, zeros beyond VOCAB) + inv norms
__global__ void k_conv_e(const float* __restrict__ E, short* __restrict__ Eb,
                         float* __restrict__ invn) {
    int lane = threadIdx.x & 63;
    int wid  = blockIdx.x * 4 + (threadIdx.x >> 6);
    int nw   = gridDim.x * 4;
    for (int r = wid; r < EB_ROWS; r += nw) {
        if (r < VOCAB) {
            const float4* p = (const float4*)(E + (size_t)r * DDIM) + lane * 2;
            float4 a = p[0], b = p[1];
            float s = a.x*a.x + a.y*a.y + a.z*a.z + a.w*a.w
                    + b.x*b.x + b.y*b.y + b.z*b.z + b.w*b.w;
            #pragma unroll
            for (int off = 32; off; off >>= 1) s += __shfl_xor(s, off, 64);
            *(uint4*)(Eb + (size_t)r * DDIM + lane * 8) = pack8(a, b);
            if (lane == 0) invn[r] = 1.0f / fmaxf(sqrtf(s), 1e-12f);
        } else {
            uint4 z; z.x = z.y = z.z = z.w = 0u;
            *(uint4*)(Eb + (size_t)r * DDIM + lane * 8) = z;
            if (lane == 0) invn[r] = 0.0f;
        }
    }
}

// ======= tier A: dual-tile A-reuse, BK=64, 2-buf __syncthreads pipeline =======

// R9/R13-verified BK=64 staging (128B per row per step -> full DRAM lines).
// Pre-swizzled source, linear dest.
__device__ __forceinline__ void stA(const short* Xb, short* Ab,
                                    int row0, int k0, int tid) {
    #pragma unroll
    for (int i = 0; i < 4; ++i) {
        int c = tid + i * 512;
        int r = c >> 3, g = c & 7;
        int gs = (g ^ (r & 7)) * 8;
        gload16(Xb + (size_t)(row0 + r) * DDIM + k0 + gs, Ab + c * 8);
    }
}
__device__ __forceinline__ void stB(const short* Eb, short* Bb,
                                    int v0, int k0, int tid) {
    #pragma unroll
    for (int i = 0; i < 2; ++i) {
        int c = tid + i * 512;
        int r = c >> 3, g = c & 7;
        int gs = (g ^ (r & 7)) * 8;
        gload16(Eb + (size_t)(v0 + r) * DDIM + k0 + gs, Bb + c * 8);
    }
}

// Dual-tile A-reuse: 24 ds_reads / 64 MFMA = 0.375/MFMA (DS pipe was the
// R13/R14 binder). R16's regression was a REGISTER SPILL: default launch
// bounds capped VGPR at 128 while live state is ~200 (acc[2][4][4]=128 +
// operands) -> +64MB scratch stores / +300MB reloads in the counters.
// Fix: __launch_bounds__(512, 2) -- 8 waves = 2/SIMD -> 256-VGPR budget.
__global__ __launch_bounds__(512, 2)
void k_gemm_fast16(const short* __restrict__ Xb, const short* __restrict__ Eb,
                   const float* __restrict__ invn, unsigned short* __restrict__ tm)
{
    extern __shared__ __align__(16) short smem[];
    short* As = smem;                            // 2 x BM2*BK (2 x 32 KB)
    short* Bs = smem + 2 * BM2 * BK;             // 2 x 2 x BN*BK (2 x 32 KB)

    const int tid  = threadIdx.x;
    const int lane = tid & 63;
    const int w    = tid >> 6;         // wave 0..7
    const int wm   = w >> 1;           // 0..3 (64-row strip)
    const int wn   = w & 1;            // 0..1 (64-col half)
    const int row0 = blockIdx.x * BM2;
    const int l15  = lane & 15, lhi = lane >> 4;

    for (int p = blockIdx.y; p < NT2; p += VC2) {
        const int t0 = 2 * p;
        const int v0 = t0 * BN, v1 = v0 + BN;
        f32x4 acc[2][4][4];
        #pragma unroll
        for (int j = 0; j < 2; ++j)
            #pragma unroll
            for (int m = 0; m < 4; ++m)
                #pragma unroll
                for (int n = 0; n < 4; ++n)
                    acc[j][m][n] = 0.0f;

        stA(Xb, As, row0, 0, tid);
        stB(Eb, Bs, v0, 0, tid);
        stB(Eb, Bs + BN * BK, v1, 0, tid);
        __syncthreads();                         // buf0 staged (vmcnt drained)

        #pragma unroll
        for (int kt = 0; kt < DDIM / BK; ++kt) {          // 8 K-steps
            const int cur = kt & 1;
            if (kt + 1 < DDIM / BK) {                     // issue K(kt+1)
                short* An = As + (cur ^ 1) * (BM2 * BK);
                short* Bn = Bs + (cur ^ 1) * (2 * BN * BK);
                stA(Xb, An, row0, (kt + 1) * BK, tid);
                stB(Eb, Bn, v0, (kt + 1) * BK, tid);
                stB(Eb, Bn + BN * BK, v1, (kt + 1) * BK, tid);
            }

            const short* Ac = As + cur * (BM2 * BK);
            const short* B0 = Bs + cur * (2 * BN * BK);
            const short* B1 = B0 + BN * BK;
            __builtin_amdgcn_s_setprio(1);
            #pragma unroll
            for (int ks = 0; ks < 2; ++ks) {
                bf16x8 av[4], bv0[4], bv1[4];
                #pragma unroll
                for (int m = 0; m < 4; ++m) {
                    int r  = wm * 64 + m * 16 + l15;
                    int ke = (ks * 32 + lhi * 8) ^ ((r & 7) << 3);
                    av[m] = *(const bf16x8*)(Ac + r * BK + ke);
                }
                #pragma unroll
                for (int n = 0; n < 4; ++n) {
                    int c  = wn * 64 + n * 16 + l15;
                    int ke = (ks * 32 + lhi * 8) ^ ((c & 7) << 3);
                    bv0[n] = *(const bf16x8*)(B0 + c * BK + ke);
                    bv1[n] = *(const bf16x8*)(B1 + c * BK + ke);
                }
                #pragma unroll
                for (int m = 0; m < 4; ++m)
                    #pragma unroll
                    for (int n = 0; n < 4; ++n) {
                        acc[0][m][n] = __builtin_amdgcn_mfma_f32_16x16x32_bf16(
                            av[m], bv0[n], acc[0][m][n], 0, 0, 0);
                        acc[1][m][n] = __builtin_amdgcn_mfma_f32_16x16x32_bf16(
                            av[m], bv1[n], acc[1][m][n], 0, 0, 0);
                    }
            }
            __builtin_amdgcn_s_setprio(0);
            __syncthreads();   // K(kt+1) landed; all readers done with cur
        }

        // shuffle-free epilogue (R15/R16-verified), once per tile of the pair.
        // col(n) = vj + wn*64 + n*16 + l15; row(m,q) = row0 + wm*64 + m*16 + lhi*4 + q
        #pragma unroll
        for (int j = 0; j < 2; ++j) {
            const int vj = v0 + j * BN;
            float inv[4];
            #pragma unroll
            for (int n = 0; n < 4; ++n) inv[n] = invn[vj + wn * 64 + n * 16 + l15];
            const int slotbase = (t0 + j) * 32 + wn * 16 + l15;
            #pragma unroll
            for (int m = 0; m < 4; ++m) {
                #pragma unroll
                for (int q = 0; q < 4; ++q) {
                    float s = fmaxf(
                        fmaxf(acc[j][m][0][q] * inv[0], acc[j][m][1][q] * inv[1]),
                        fmaxf(acc[j][m][2][q] * inv[2], acc[j][m][3][q] * inv[3]));
                    int row = row0 + wm * 64 + m * 16 + lhi * 4 + q;
                    tm[(size_t)row * TW16 + slotbase] = __half_as_ushort(__float2half(s));
                }
            }
        }
        // no extra barrier: next pair's stage targets buf0, whose readers all
        // passed the kt=6/7 barriers; the post-stage __syncthreads drains vmcnt.
    }
}

// one wave per row: rowmax over 12608 f16 slots, append candidates; inits keys
// list entry = (row << 14) | slot
__global__ void k_select16(const unsigned short* __restrict__ tm,
                           unsigned* __restrict__ list, unsigned* __restrict__ cnt,
                           unsigned long long* __restrict__ keys) {
    int row  = blockIdx.x * 4 + (threadIdx.x >> 6);
    int lane = threadIdx.x & 63;
    if (lane == 0) keys[row] = 0ull;
    const unsigned short* p = tm + (size_t)row * TW16;
    float m = -INFINITY;
    for (int c = lane; c < TW16 / 8; c += 64) {
        bf16x8 v = *(const bf16x8*)(p + c * 8);
        #pragma unroll
        for (int k = 0; k < 8; ++k)
            m = fmaxf(m, __half2float(__ushort_as_half((unsigned short)v[k])));
    }
    #pragma unroll
    for (int off = 32; off; off >>= 1) m = fmaxf(m, __shfl_xor(m, off, 64));
    float th = m - TAU16;
    for (int c = lane; c < TW16 / 8; c += 64) {
        bf16x8 v = *(const bf16x8*)(p + c * 8);
        #pragma unroll
        for (int k = 0; k < 8; ++k) {
            if (__half2float(__ushort_as_half((unsigned short)v[k])) >= th) {
                unsigned slot = atomicAdd(cnt, 1u);
                if (slot < LISTCAP)
                    list[slot] = ((unsigned)row << 14) | (unsigned)(c * 8 + k);
            }
        }
    }
}

// exact fp64 rescore of one 4-col slot group per wave.
// slot -> t = slot>>5, wn = (slot>>4)&1, l15 = slot&15; cols = t*128+wn*64+n*16+l15
__global__ __launch_bounds__(256)
void k_rescore4(const float* __restrict__ X, const float* __restrict__ E,
                const float* __restrict__ invn,
                const unsigned* __restrict__ list, const unsigned* __restrict__ cnt,
                unsigned long long* __restrict__ keys) {
    unsigned n = *cnt; if (n > LISTCAP) n = LISTCAP;
    int lane = (int)threadIdx.x & 63;
    int nn   = lane >> 4;              // which of the 4 cols
    int part = lane & 15;              // 16-way split of the dot product
    unsigned wv = blockIdx.x * 4 + ((unsigned)threadIdx.x >> 6);
    unsigned nw = gridDim.x * 4;
    for (unsigned ci = wv; ci < n; ci += nw) {
        unsigned e = list[ci];
        int row  = (int)(e >> 14);
        int slot = (int)(e & 16383u);
        int col  = (slot >> 5) * 128 + ((slot >> 4) & 1) * 64 + nn * 16 + (slot & 15);
        if (col < VOCAB) {
            const float4* xp = (const float4*)(X + (size_t)row * DDIM + part * 32);
            const float4* ep = (const float4*)(E + (size_t)col * DDIM + part * 32);
            double s = 0.0;
            #pragma unroll
            for (int d = 0; d < 8; ++d) {
                float4 a = xp[d], b = ep[d];
                s = fma((double)a.x, (double)b.x, s);
                s = fma((double)a.y, (double)b.y, s);
                s = fma((double)a.z, (double)b.z, s);
                s = fma((double)a.w, (double)b.w, s);
            }
            s += __shfl_xor(s, 1, 64);
            s += __shfl_xor(s, 2, 64);
            s += __shfl_xor(s, 4, 64);
            s += __shfl_xor(s, 8, 64);
            if (part == 0) {
                float fs = (float)(s * (double)invn[col]);
                unsigned long long key = ((unsigned long long)enc_f32(fs) << 32)
                                       | (unsigned long long)(0xffffffffu - (unsigned)col);
                atomicMax(keys + row, key);
            }
        }
    }
}

__global__ void k_final(const unsigned long long* __restrict__ keys,
                        int* __restrict__ out) {
    int i = blockIdx.x * 256 + threadIdx.x;
    if (i < NROWS)
        out[i] = (int)(0xffffffffu - (unsigned int)(keys[i] & 0xffffffffull));
}

// ==================== tier B: R6-verified f32 half-tile path ====================

__global__ __launch_bounds__(512)
void k_gemm_fast1(const short* __restrict__ Xb, const short* __restrict__ Eb,
                  const float* __restrict__ invn, float* __restrict__ tm)
{
    constexpr int TW = NT * 2;
    __shared__ __align__(16) short Ab[BM2 * BK];
    __shared__ __align__(16) short Bb[BN  * BK];

    const int tid  = threadIdx.x;
    const int lane = tid & 63;
    const int w    = tid >> 6;
    const int wm   = w >> 1;
    const int wn   = w & 1;
    const int row0 = blockIdx.x * BM2;
    const int l15  = lane & 15, lhi = lane >> 4;

    for (int t = blockIdx.y; t < NT; t += VC2) {
        const int v0 = t * BN;
        f32x4 acc[4][4];
        #pragma unroll
        for (int m = 0; m < 4; ++m)
            #pragma unroll
            for (int n = 0; n < 4; ++n)
                acc[m][n] = 0.0f;

        for (int kt = 0; kt < DDIM / BK; ++kt) {
            const int k0 = kt * BK;
            #pragma unroll
            for (int i = 0; i < 4; ++i) {
                int c = tid + i * 512;
                int r = c >> 3, g = c & 7;
                int gs = (g ^ (r & 7)) * 8;
                gload16(Xb + (size_t)(row0 + r) * DDIM + k0 + gs, Ab + c * 8);
            }
            #pragma unroll
            for (int i = 0; i < 2; ++i) {
                int c = tid + i * 512;
                int r = c >> 3, g = c & 7;
                int gs = (g ^ (r & 7)) * 8;
                gload16(Eb + (size_t)(v0 + r) * DDIM + k0 + gs, Bb + c * 8);
            }
            __syncthreads();
            #pragma unroll
            for (int ks = 0; ks < 2; ++ks) {
                bf16x8 av[4], bv[4];
                #pragma unroll
                for (int m = 0; m < 4; ++m) {
                    int r  = wm * 64 + m * 16 + l15;
                    int ke = (ks * 32 + lhi * 8) ^ ((r & 7) << 3);
                    av[m] = *(const bf16x8*)(Ab + r * BK + ke);
                }
                #pragma unroll
                for (int n = 0; n < 4; ++n) {
                    int c  = wn * 64 + n * 16 + l15;
                    int ke = (ks * 32 + lhi * 8) ^ ((c & 7) << 3);
                    bv[n] = *(const bf16x8*)(Bb + c * BK + ke);
                }
                #pragma unroll
                for (int m = 0; m < 4; ++m)
                    #pragma unroll
                    for (int n = 0; n < 4; ++n)
                        acc[m][n] = __builtin_amdgcn_mfma_f32_16x16x32_bf16(
                            av[m], bv[n], acc[m][n], 0, 0, 0);
            }
            __syncthreads();
        }

        float inv[4];
        #pragma unroll
        for (int n = 0; n < 4; ++n) inv[n] = invn[v0 + wn * 64 + n * 16 + l15];
        #pragma unroll
        for (int m = 0; m < 4; ++m) {
            #pragma unroll
            for (int j = 0; j < 4; ++j) {
                float v = fmaxf(fmaxf(acc[m][0][j] * inv[0], acc[m][1][j] * inv[1]),
                                fmaxf(acc[m][2][j] * inv[2], acc[m][3][j] * inv[3]));
                #pragma unroll
                for (int off = 1; off < 16; off <<= 1)
                    v = fmaxf(v, __shfl_xor(v, off, 64));
                if (l15 == 0) {
                    int row = row0 + wm * 64 + m * 16 + lhi * 4 + j;
                    tm[(size_t)row * TW + t * 2 + wn] = v;
                }
            }
        }
    }
}

__global__ void k_select1(const float* __restrict__ tm,
                          unsigned* __restrict__ list, unsigned* __restrict__ cnt,
                          unsigned long long* __restrict__ keys) {
    constexpr int TW = NT * 2;
    int row  = blockIdx.x * 4 + (threadIdx.x >> 6);
    int lane = threadIdx.x & 63;
    if (lane == 0) keys[row] = 0ull;
    const float* p = tm + (size_t)row * TW;
    float m = -INFINITY;
    for (int i = lane; i < TW; i += 64) m = fmaxf(m, p[i]);
    #pragma unroll
    for (int off = 32; off; off >>= 1) m = fmaxf(m, __shfl_xor(m, off, 64));
    float th = m - TAU1;
    for (int i = lane; i < TW; i += 64) {
        if (p[i] >= th) {
            unsigned slot = atomicAdd(cnt, 1u);
            if (slot < LISTCAP) list[slot] = ((unsigned)row << 14) | (unsigned)i;
        }
    }
}

__global__ __launch_bounds__(256)
void k_rescore64(const float* __restrict__ X, const float* __restrict__ E,
                 const float* __restrict__ invn,
                 const unsigned* __restrict__ list, const unsigned* __restrict__ cnt,
                 unsigned long long* __restrict__ keys) {
    unsigned n = *cnt; if (n > LISTCAP) n = LISTCAP;
    for (unsigned ci = blockIdx.x; ci < n; ci += gridDim.x) {
        unsigned e = list[ci];
        int row = (int)(e >> 14);
        int idx = (int)(e & 16383u);
        int v0  = (idx >> 1) * BN + (idx & 1) * 64;
        int col  = v0 + ((int)threadIdx.x >> 2);
        int part = (int)threadIdx.x & 3;
        if (col < VOCAB) {
            const float4* xp = (const float4*)(X + (size_t)row * DDIM + part * 128);
            const float4* ep = (const float4*)(E + (size_t)col * DDIM + part * 128);
            double s = 0.0;
            #pragma unroll 8
            for (int d = 0; d < 32; ++d) {
                float4 a = xp[d], b = ep[d];
                s = fma((double)a.x, (double)b.x, s);
                s = fma((double)a.y, (double)b.y, s);
                s = fma((double)a.z, (double)b.z, s);
                s = fma((double)a.w, (double)b.w, s);
            }
            s += __shfl_xor(s, 1, 64);
            s += __shfl_xor(s, 2, 64);
            if (part == 0) {
                float fs = (float)(s * (double)invn[col]);
                unsigned long long key = ((unsigned long long)enc_f32(fs) << 32)
                                       | (unsigned long long)(0xffffffffu - (unsigned)col);
                atomicMax(keys + row, key);
            }
        }
    }
}

// ===================== fallback path (round-1, verified) =====================

#define BM 128
#define VC 33

__global__ void k_init_fb(unsigned int* rowmax, unsigned long long* keys) {
    int i = blockIdx.x * 256 + threadIdx.x;
    if (i < NROWS) { rowmax[i] = 0u; keys[i] = 0ull; }
}

__global__ void k_enorm(const float* __restrict__ E, float* __restrict__ invn) {
    int lane = threadIdx.x & 63;
    int wid  = blockIdx.x * 4 + (threadIdx.x >> 6);
    int nw   = gridDim.x * 4;
    for (int r = wid; r < VOCAB; r += nw) {
        const float4* p = (const float4*)(E + (size_t)r * DDIM);
        float4 a = p[lane];
        float4 b = p[lane + 64];
        float s = a.x*a.x + a.y*a.y + a.z*a.z + a.w*a.w
                + b.x*b.x + b.y*b.y + b.z*b.z + b.w*b.w;
        #pragma unroll
        for (int off = 32; off; off >>= 1) s += __shfl_xor(s, off, 64);
        if (lane == 0) invn[r] = 1.0f / fmaxf(sqrtf(s), 1e-12f);
    }
}

__device__ __noinline__ void rescore1(const float* __restrict__ X,
                                      const float* __restrict__ E,
                                      float iv, int row, int col,
                                      unsigned long long* keys) {
    const float4* xp = (const float4*)(X + (size_t)row * DDIM);
    const float4* ep = (const float4*)(E + (size_t)col * DDIM);
    double a0 = 0.0, a1 = 0.0, a2 = 0.0, a3 = 0.0;
    for (int d = 0; d < DDIM / 4; ++d) {
        float4 x4 = xp[d], e4 = ep[d];
        a0 = fma((double)x4.x, (double)e4.x, a0);
        a1 = fma((double)x4.y, (double)e4.y, a1);
        a2 = fma((double)x4.z, (double)e4.z, a2);
        a3 = fma((double)x4.w, (double)e4.w, a3);
    }
    float fs = (float)((((a0 + a1) + (a2 + a3))) * (double)iv);
    unsigned long long key = ((unsigned long long)enc_f32(fs) << 32)
                           | (unsigned long long)(0xffffffffu - (unsigned int)col);
    atomicMax(keys + row, key);
}

template <int PASS>
__global__ __launch_bounds__(256, 2)
void k_gemm_fb(const float* __restrict__ X, const float* __restrict__ E,
               const float* __restrict__ invn,
               unsigned int* __restrict__ rowmax,
               unsigned long long* __restrict__ keys)
{
    __shared__ __align__(16) short Abuf[BM * BK];
    __shared__ __align__(16) short Bbuf[BN * BK];

    const int tid  = threadIdx.x;
    const int lane = tid & 63;
    const int w    = tid >> 6;
    const int wm   = w >> 1, wn = w & 1;
    const int row0 = blockIdx.y * BM;
    const int l15  = lane & 15, lhi = lane >> 4;

    float rmax[4][4];
    float thr[4][4];
    #pragma unroll
    for (int m = 0; m < 4; ++m)
        #pragma unroll
        for (int j = 0; j < 4; ++j) {
            rmax[m][j] = -INFINITY;
            if (PASS == 2) {
                int row = row0 + wm * 64 + m * 16 + lhi * 4 + j;
                thr[m][j] = dec_f32(rowmax[row]) - TAU1;
            }
        }

    for (int t = blockIdx.x; t < NT; t += VC) {
        const int v0 = t * BN;
        f32x4 acc[4][4];
        #pragma unroll
        for (int m = 0; m < 4; ++m)
            #pragma unroll
            for (int n = 0; n < 4; ++n)
                acc[m][n] = 0.0f;

        for (int kt = 0; kt < DDIM / BK; ++kt) {
            const int k0 = kt * BK;
            #pragma unroll
            for (int i = 0; i < 4; ++i) {
                int f  = tid + i * 256;
                int r  = f >> 3;
                int ks = (f & 7) * 8;
                const float* src = X + (size_t)(row0 + r) * DDIM + k0 + ks;
                float4 aa = *(const float4*)src;
                float4 bb = *(const float4*)(src + 4);
                *(uint4*)(Abuf + r * BK + (ks ^ ((r & 7) << 3))) = pack8(aa, bb);
            }
            #pragma unroll
            for (int i = 0; i < 4; ++i) {
                int f  = tid + i * 256;
                int r  = f >> 3;
                int ks = (f & 7) * 8;
                float4 aa = {0.f,0.f,0.f,0.f}, bb = {0.f,0.f,0.f,0.f};
                if (v0 + r < VOCAB) {
                    const float* src = E + (size_t)(v0 + r) * DDIM + k0 + ks;
                    aa = *(const float4*)src;
                    bb = *(const float4*)(src + 4);
                }
                *(uint4*)(Bbuf + r * BK + (ks ^ ((r & 7) << 3))) = pack8(aa, bb);
            }
            __syncthreads();
            #pragma unroll
            for (int ks = 0; ks < 2; ++ks) {
                bf16x8 av[4], bv[4];
                #pragma unroll
                for (int m = 0; m < 4; ++m) {
                    int r  = wm * 64 + m * 16 + l15;
                    int ke = (ks * 32 + lhi * 8) ^ ((r & 7) << 3);
                    av[m] = *(const bf16x8*)(Abuf + r * BK + ke);
                }
                #pragma unroll
                for (int n = 0; n < 4; ++n) {
                    int c  = wn * 64 + n * 16 + l15;
                    int ke = (ks * 32 + lhi * 8) ^ ((c & 7) << 3);
                    bv[n] = *(const bf16x8*)(Bbuf + c * BK + ke);
                }
                #pragma unroll
                for (int m = 0; m < 4; ++m)
                    #pragma unroll
                    for (int n = 0; n < 4; ++n)
                        acc[m][n] = __builtin_amdgcn_mfma_f32_16x16x32_bf16(
                            av[m], bv[n], acc[m][n], 0, 0, 0);
            }
            __syncthreads();
        }

        float inv[4]; int colv[4];
        #pragma unroll
        for (int n = 0; n < 4; ++n) {
            int c = v0 + wn * 64 + n * 16 + l15;
            colv[n] = c;
            inv[n] = (c < VOCAB) ? invn[c] : 0.0f;
        }
        if (PASS == 1) {
            #pragma unroll
            for (int m = 0; m < 4; ++m)
                #pragma unroll
                for (int n = 0; n < 4; ++n)
                    if (colv[n] < VOCAB) {
                        #pragma unroll
                        for (int j = 0; j < 4; ++j)
                            rmax[m][j] = fmaxf(rmax[m][j], acc[m][n][j] * inv[n]);
                    }
        } else {
            #pragma unroll
            for (int m = 0; m < 4; ++m)
                #pragma unroll
                for (int n = 0; n < 4; ++n)
                    if (colv[n] < VOCAB) {
                        #pragma unroll
                        for (int j = 0; j < 4; ++j) {
                            float sc = acc[m][n][j] * inv[n];
                            if (sc >= thr[m][j]) {
                                int row = row0 + wm * 64 + m * 16 + lhi * 4 + j;
                                rescore1(X, E, inv[n], row, colv[n], keys);
                            }
                        }
                    }
        }
    }

    if (PASS == 1) {
        #pragma unroll
        for (int m = 0; m < 4; ++m)
            #pragma unroll
            for (int j = 0; j < 4; ++j) {
                float v = rmax[m][j];
                #pragma unroll
                for (int off = 1; off < 16; off <<= 1)
                    v = fmaxf(v, __shfl_xor(v, off, 64));
                if (l15 == 0) {
                    int row = row0 + wm * 64 + m * 16 + lhi * 4 + j;
                    atomicMax(rowmax + row, enc_f32(v));
                }
            }
    }
}

// =============================== launch ===============================

extern "C" void kernel_launch(void* const* d_in, const int* in_sizes, int n_in,
                              void* d_out, int out_size, void* d_ws, size_t ws_size,
                              hipStream_t stream) {
    const float* X = (const float*)d_in[0];   // (4096, 512)
    const float* E = (const float*)d_in[1];   // (50257, 512)
    int* out = (int*)d_out;                   // (4096,) int32
    char* ws = (char*)d_ws;

    const size_t sz_Eb    = (size_t)EB_ROWS * DDIM * 2;          // 51,642,368
    const size_t sz_Xb    = (size_t)NROWS * DDIM * 2;            //  4,194,304
    const size_t sz_invn  = (size_t)EB_ROWS * 4;                 //    201,728
    const size_t sz_keys  = (size_t)NROWS * 8;
    const size_t sz_list  = (size_t)LISTCAP * 4;
    const size_t fixed    = sz_Eb + sz_Xb + sz_invn + sz_keys + sz_list + 256;
    const size_t sz_tm16  = (size_t)NROWS * TW16 * 2;            // 103,284,736
    const size_t sz_tm1   = (size_t)NROWS * (NT * 2) * 4;        // 12,877,824

    int tier = 0;
    if (ws_size >= fixed + sz_tm16)     tier = 16;
    else if (ws_size >= fixed + sz_tm1) tier = 1;

    if (tier) {
        const size_t sz_tm = (tier == 16) ? sz_tm16 : sz_tm1;
        short* Eb   = (short*)(ws);
        short* Xb   = (short*)(ws + sz_Eb);
        float* invn = (float*)(ws + sz_Eb + sz_Xb);
        char*  tmb  = ws + sz_Eb + sz_Xb + sz_invn;
        unsigned long long* keys = (unsigned long long*)(tmb + sz_tm);
        unsigned* list = (unsigned*)((char*)keys + sz_keys);
        unsigned* cnt  = (unsigned*)((char*)list + sz_list);

        k_conv_x<<<(NROWS * DDIM / 8) / 256, 256, 0, stream>>>(X, Xb, cnt);
        k_conv_e<<<2048, 256, 0, stream>>>(E, Eb, invn);
        dim3 g(RB2, VC2);
        if (tier == 16) {
            const size_t smem = (size_t)2 * (BM2 * BK + 2 * BN * BK) * sizeof(short); // 128 KB
            k_gemm_fast16<<<g, 512, smem, stream>>>(Xb, Eb, invn, (unsigned short*)tmb);
            k_select16<<<NROWS / 4, 256, 0, stream>>>((unsigned short*)tmb, list, cnt, keys);
            k_rescore4<<<2048, 256, 0, stream>>>(X, E, invn, list, cnt, keys);
        } else {
            k_gemm_fast1<<<g, 512, 0, stream>>>(Xb, Eb, invn, (float*)tmb);
            k_select1<<<NROWS / 4, 256, 0, stream>>>((float*)tmb, list, cnt, keys);
            k_rescore64<<<2048, 256, 0, stream>>>(X, E, invn, list, cnt, keys);
        }
        k_final<<<(NROWS + 255) / 256, 256, 0, stream>>>(keys, out);
    } else {
        // fallback: round-1 verified two-pass path (small ws)
        float* invn = (float*)ws;
        size_t off0 = ((size_t)VOCAB * 4 + 255) & ~(size_t)255;
        unsigned int* rowmax = (unsigned int*)(ws + off0);
        size_t off1 = off0 + (((size_t)NROWS * 4 + 255) & ~(size_t)255);
        unsigned long long* keys = (unsigned long long*)(ws + off1);

        k_init_fb<<<(NROWS + 255) / 256, 256, 0, stream>>>(rowmax, keys);
        k_enorm<<<1024, 256, 0, stream>>>(E, invn);
        dim3 g(VC, NROWS / BM);
        k_gemm_fb<1><<<g, 256, 0, stream>>>(X, E, invn, rowmax, keys);
        k_gemm_fb<2><<<g, 256, 0, stream>>>(X, E, invn, rowmax, keys);
        k_final<<<(NROWS + 255) / 256, 256, 0, stream>>>(keys, out);
    }
}

// Round 18
// 308.153 us; speedup vs baseline: 1.4818x; 1.4788x over previous
//
#include <hip/hip_runtime.h>
#include <hip/hip_bf16.h>
#include <hip/hip_fp16.h>
#include <stdint.h>

// Problem constants (setup_inputs is fixed-shape)
#define DDIM  512
#define NROWS 4096            // 8*512 query rows
#define VOCAB 50257
#define BM2 256               // gemm row-tile
#define BN 128
#define BK 64
#define NT ((VOCAB + BN - 1) / BN)   // 393 col tiles
#define VC2 16                       // vocab chunks -> 16*16=256 blocks = 1/CU
                                     // (R13-verified: removes tail quantization)
#define RB2 (NROWS / BM2)            // 16 row blocks
#define EB_ROWS (NT * BN)            // 50304 (padded vocab rows)
#define TW16 (NT * 32)               // 12576 4-col slots per row (f16 tm)
#define TAU16 0.04f                  // margin: mfma chain (~0.01) + 2x f16 rnd (0.004)
#define TAU1  0.02f                  // tier-B margin (f32 tm, R6-verified)
#define LISTCAP (1 << 18)

typedef short bf16x8 __attribute__((ext_vector_type(8)));
typedef float f32x4  __attribute__((ext_vector_type(4)));

// order-preserving encode of fp32 into uint32 (for atomicMax)
__device__ __forceinline__ unsigned int enc_f32(float f) {
    unsigned int u = __float_as_uint(f);
    return (u & 0x80000000u) ? ~u : (u | 0x80000000u);
}
__device__ __forceinline__ float dec_f32(unsigned int e) {
    unsigned int u = (e & 0x80000000u) ? (e & 0x7fffffffu) : ~e;
    return __uint_as_float(u);
}
__device__ __forceinline__ unsigned short bf16_rne(float f) {
    unsigned int u = __float_as_uint(f);
    u += 0x7fffu + ((u >> 16) & 1u);
    return (unsigned short)(u >> 16);
}
__device__ __forceinline__ void gload16(const short* g, short* l) {
    __builtin_amdgcn_global_load_lds(
        (const __attribute__((address_space(1))) void*)g,
        (__attribute__((address_space(3))) void*)l, 16, 0, 0);
}
__device__ __forceinline__ uint4 pack8(float4 a, float4 b) {
    uint4 wv;
    wv.x = ((unsigned)bf16_rne(a.y) << 16) | bf16_rne(a.x);
    wv.y = ((unsigned)bf16_rne(a.w) << 16) | bf16_rne(a.z);
    wv.z = ((unsigned)bf16_rne(b.y) << 16) | bf16_rne(b.x);
    wv.w = ((unsigned)bf16_rne(b.w) << 16) | bf16_rne(b.z);
    return wv;
}

// ============================ shared prep ============================

// X fp32 -> bf16 (4096x512); also zeroes candidate counter
__global__ void k_conv_x(const float* __restrict__ X, short* __restrict__ Xb,
                         unsigned* __restrict__ cnt) {
    int i = blockIdx.x * 256 + threadIdx.x;        // one 8-elem group per thread
    if (i == 0) *cnt = 0u;
    const float4* p = (const float4*)X + (size_t)i * 2;
    float4 a = p[0], b = p[1];
    *(uint4*)(Xb + (size_t)i * 8) = pack8(a, b);
}

// E fp32 -> bf16 (padded to EB_ROWS, zeros beyond VOCAB) + inv norms
__global__ void k_conv_e(const float* __restrict__ E, short* __restrict__ Eb,
                         float* __restrict__ invn) {
    int lane = threadIdx.x & 63;
    int wid  = blockIdx.x * 4 + (threadIdx.x >> 6);
    int nw   = gridDim.x * 4;
    for (int r = wid; r < EB_ROWS; r += nw) {
        if (r < VOCAB) {
            const float4* p = (const float4*)(E + (size_t)r * DDIM) + lane * 2;
            float4 a = p[0], b = p[1];
            float s = a.x*a.x + a.y*a.y + a.z*a.z + a.w*a.w
                    + b.x*b.x + b.y*b.y + b.z*b.z + b.w*b.w;
            #pragma unroll
            for (int off = 32; off; off >>= 1) s += __shfl_xor(s, off, 64);
            *(uint4*)(Eb + (size_t)r * DDIM + lane * 8) = pack8(a, b);
            if (lane == 0) invn[r] = 1.0f / fmaxf(sqrtf(s), 1e-12f);
        } else {
            uint4 z; z.x = z.y = z.z = z.w = 0u;
            *(uint4*)(Eb + (size_t)r * DDIM + lane * 8) = z;
            if (lane == 0) invn[r] = 0.0f;
        }
    }
}

// ==================== tier A: 3-buf counted-vmcnt pipeline, f16 tm ====================
// R13-verified configuration (best measured: gemm 207us, MfmaUtil 45.6%,
// total 309.6us). R16/R17's dual-tile variant is parked: the toolchain caps
// 512-thread kernels at 128 VGPRs regardless of launch-bounds 2nd arg
// (two HW data points), and the dual-tile working set (~190 regs) spills.

// R9-verified staging bodies (pre-swizzled global source, linear LDS dest)
__device__ __forceinline__ void stageA3(const short* Xb, short* Ab,
                                        int row0, int k0, int tid) {
    #pragma unroll
    for (int i = 0; i < 4; ++i) {
        int c = tid + i * 512;
        int r = c >> 3, g = c & 7;
        int gs = (g ^ (r & 7)) * 8;
        gload16(Xb + (size_t)(row0 + r) * DDIM + k0 + gs, Ab + c * 8);
    }
}
__device__ __forceinline__ void stageB3(const short* Eb, short* Bb,
                                        int v0, int k0, int tid) {
    #pragma unroll
    for (int i = 0; i < 2; ++i) {
        int c = tid + i * 512;
        int r = c >> 3, g = c & 7;
        int gs = (g ^ (r & 7)) * 8;
        gload16(Eb + (size_t)(v0 + r) * DDIM + k0 + gs, Bb + c * 8);
    }
}

// Pipeline (R12/R13-verified): step kt computes buf[kt%3] while K(kt+2)'s
// loads (issued this step, 6/wave) and K(kt+1)'s (issued last step) are in
// flight. End-of-step wait = counted vmcnt(6) + ONE raw s_barrier.
// buf[(kt+2)%3] was last read at step kt-1 and released at its barrier ->
// write-safe. One full vmcnt(0) drain per tile (epilogue), not per step.
__global__ __launch_bounds__(512)
void k_gemm_fast16(const short* __restrict__ Xb, const short* __restrict__ Eb,
                   const float* __restrict__ invn, unsigned short* __restrict__ tm)
{
    extern __shared__ __align__(16) short smem[];
    short* As = smem;                        // 3 x BM2*BK shorts (3 x 32 KB)
    short* Bs = smem + 3 * BM2 * BK;         // 3 x BN*BK shorts  (3 x 16 KB)

    const int tid  = threadIdx.x;
    const int lane = tid & 63;
    const int w    = tid >> 6;         // wave 0..7
    const int wm   = w >> 1;           // 0..3 (64-row strip)
    const int wn   = w & 1;            // 0..1 (64-col half)
    const int row0 = blockIdx.x * BM2;
    const int l15  = lane & 15, lhi = lane >> 4;

    for (int t = blockIdx.y; t < NT; t += VC2) {
        const int v0 = t * BN;
        f32x4 acc[4][4];
        #pragma unroll
        for (int m = 0; m < 4; ++m)
            #pragma unroll
            for (int n = 0; n < 4; ++n)
                acc[m][n] = 0.0f;

        // prologue: issue K0 -> buf0, K1 -> buf1; wait K0 (6 left = K1)
        stageA3(Xb, As, row0, 0, tid);
        stageB3(Eb, Bs, v0, 0, tid);
        stageA3(Xb, As + BM2 * BK, row0, BK, tid);
        stageB3(Eb, Bs + BN * BK, v0, BK, tid);
        asm volatile("s_waitcnt vmcnt(6)" ::: "memory");
        __builtin_amdgcn_s_barrier();
        __builtin_amdgcn_sched_barrier(0);

        #pragma unroll
        for (int kt = 0; kt < DDIM / BK; ++kt) {        // 8 K-steps
            const short* Ac = As + (kt % 3) * (BM2 * BK);
            const short* Bc = Bs + (kt % 3) * (BN * BK);
            if (kt + 2 < DDIM / BK) {                   // issue K(kt+2)
                short* An = As + ((kt + 2) % 3) * (BM2 * BK);
                short* Bn = Bs + ((kt + 2) % 3) * (BN * BK);
                stageA3(Xb, An, row0, (kt + 2) * BK, tid);
                stageB3(Eb, Bn, v0, (kt + 2) * BK, tid);
            }

            #pragma unroll
            for (int ks = 0; ks < 2; ++ks) {
                bf16x8 av[4], bv[4];
                #pragma unroll
                for (int m = 0; m < 4; ++m) {
                    int r  = wm * 64 + m * 16 + l15;
                    int ke = (ks * 32 + lhi * 8) ^ ((r & 7) << 3);
                    av[m] = *(const bf16x8*)(Ac + r * BK + ke);
                }
                #pragma unroll
                for (int n = 0; n < 4; ++n) {
                    int c  = wn * 64 + n * 16 + l15;
                    int ke = (ks * 32 + lhi * 8) ^ ((c & 7) << 3);
                    bv[n] = *(const bf16x8*)(Bc + c * BK + ke);
                }
                #pragma unroll
                for (int m = 0; m < 4; ++m)
                    #pragma unroll
                    for (int n = 0; n < 4; ++n)
                        acc[m][n] = __builtin_amdgcn_mfma_f32_16x16x32_bf16(
                            av[m], bv[n], acc[m][n], 0, 0, 0);
            }

            if (kt < DDIM / BK - 1) {
                if (kt + 2 < DDIM / BK)
                    asm volatile("s_waitcnt vmcnt(6)" ::: "memory"); // K(kt+1) done
                else
                    asm volatile("s_waitcnt vmcnt(0)" ::: "memory"); // tail
                __builtin_amdgcn_s_barrier();
                __builtin_amdgcn_sched_barrier(0);
            }
        }

        // shuffle-free epilogue (R9-verified). col(n) = v0 + wn*64 + n*16 + l15;
        // row(m,j) = row0 + wm*64 + m*16 + lhi*4 + j
        float inv[4];
        #pragma unroll
        for (int n = 0; n < 4; ++n) inv[n] = invn[v0 + wn * 64 + n * 16 + l15];
        const int slotbase = t * 32 + wn * 16 + l15;
        #pragma unroll
        for (int m = 0; m < 4; ++m) {
            #pragma unroll
            for (int j = 0; j < 4; ++j) {
                float s = fmaxf(fmaxf(acc[m][0][j] * inv[0], acc[m][1][j] * inv[1]),
                                fmaxf(acc[m][2][j] * inv[2], acc[m][3][j] * inv[3]));
                int row = row0 + wm * 64 + m * 16 + lhi * 4 + j;
                tm[(size_t)row * TW16 + slotbase] = __half_as_ushort(__float2half(s));
            }
        }

        // one full drain per tile: stores retired, LDS reusable, vmcnt clean
        asm volatile("s_waitcnt vmcnt(0)" ::: "memory");
        __builtin_amdgcn_s_barrier();
        __builtin_amdgcn_sched_barrier(0);
    }
}

// one wave per row: rowmax over 12576 f16 slots, append candidates; inits keys
// list entry = (row << 14) | slot
__global__ void k_select16(const unsigned short* __restrict__ tm,
                           unsigned* __restrict__ list, unsigned* __restrict__ cnt,
                           unsigned long long* __restrict__ keys) {
    int row  = blockIdx.x * 4 + (threadIdx.x >> 6);
    int lane = threadIdx.x & 63;
    if (lane == 0) keys[row] = 0ull;
    const unsigned short* p = tm + (size_t)row * TW16;
    float m = -INFINITY;
    // vectorized: 8 f16 per lane per iter; TW16/8 = 1572 chunks
    for (int c = lane; c < TW16 / 8; c += 64) {
        bf16x8 v = *(const bf16x8*)(p + c * 8);
        #pragma unroll
        for (int k = 0; k < 8; ++k)
            m = fmaxf(m, __half2float(__ushort_as_half((unsigned short)v[k])));
    }
    #pragma unroll
    for (int off = 32; off; off >>= 1) m = fmaxf(m, __shfl_xor(m, off, 64));
    float th = m - TAU16;
    for (int c = lane; c < TW16 / 8; c += 64) {
        bf16x8 v = *(const bf16x8*)(p + c * 8);
        #pragma unroll
        for (int k = 0; k < 8; ++k) {
            if (__half2float(__ushort_as_half((unsigned short)v[k])) >= th) {
                unsigned slot = atomicAdd(cnt, 1u);
                if (slot < LISTCAP)
                    list[slot] = ((unsigned)row << 14) | (unsigned)(c * 8 + k);
            }
        }
    }
}

// exact fp64 rescore of one 4-col slot group per wave.
// slot -> t = slot>>5, wn = (slot>>4)&1, l15 = slot&15; cols = t*128+wn*64+n*16+l15
__global__ __launch_bounds__(256)
void k_rescore4(const float* __restrict__ X, const float* __restrict__ E,
                const float* __restrict__ invn,
                const unsigned* __restrict__ list, const unsigned* __restrict__ cnt,
                unsigned long long* __restrict__ keys) {
    unsigned n = *cnt; if (n > LISTCAP) n = LISTCAP;
    int lane = (int)threadIdx.x & 63;
    int nn   = lane >> 4;              // which of the 4 cols
    int part = lane & 15;              // 16-way split of the dot product
    unsigned wv = blockIdx.x * 4 + ((unsigned)threadIdx.x >> 6);
    unsigned nw = gridDim.x * 4;
    for (unsigned ci = wv; ci < n; ci += nw) {
        unsigned e = list[ci];
        int row  = (int)(e >> 14);
        int slot = (int)(e & 16383u);
        int col  = (slot >> 5) * 128 + ((slot >> 4) & 1) * 64 + nn * 16 + (slot & 15);
        if (col < VOCAB) {
            const float4* xp = (const float4*)(X + (size_t)row * DDIM + part * 32);
            const float4* ep = (const float4*)(E + (size_t)col * DDIM + part * 32);
            double s = 0.0;
            #pragma unroll
            for (int d = 0; d < 8; ++d) {
                float4 a = xp[d], b = ep[d];
                s = fma((double)a.x, (double)b.x, s);
                s = fma((double)a.y, (double)b.y, s);
                s = fma((double)a.z, (double)b.z, s);
                s = fma((double)a.w, (double)b.w, s);
            }
            s += __shfl_xor(s, 1, 64);
            s += __shfl_xor(s, 2, 64);
            s += __shfl_xor(s, 4, 64);
            s += __shfl_xor(s, 8, 64);
            if (part == 0) {
                float fs = (float)(s * (double)invn[col]);
                unsigned long long key = ((unsigned long long)enc_f32(fs) << 32)
                                       | (unsigned long long)(0xffffffffu - (unsigned)col);
                atomicMax(keys + row, key);
            }
        }
    }
}

__global__ void k_final(const unsigned long long* __restrict__ keys,
                        int* __restrict__ out) {
    int i = blockIdx.x * 256 + threadIdx.x;
    if (i < NROWS)
        out[i] = (int)(0xffffffffu - (unsigned int)(keys[i] & 0xffffffffull));
}

// ==================== tier B: R6-verified f32 half-tile path ====================

__global__ __launch_bounds__(512)
void k_gemm_fast1(const short* __restrict__ Xb, const short* __restrict__ Eb,
                  const float* __restrict__ invn, float* __restrict__ tm)
{
    constexpr int TW = NT * 2;
    __shared__ __align__(16) short Ab[BM2 * BK];
    __shared__ __align__(16) short Bb[BN  * BK];

    const int tid  = threadIdx.x;
    const int lane = tid & 63;
    const int w    = tid >> 6;
    const int wm   = w >> 1;
    const int wn   = w & 1;
    const int row0 = blockIdx.x * BM2;
    const int l15  = lane & 15, lhi = lane >> 4;

    for (int t = blockIdx.y; t < NT; t += VC2) {
        const int v0 = t * BN;
        f32x4 acc[4][4];
        #pragma unroll
        for (int m = 0; m < 4; ++m)
            #pragma unroll
            for (int n = 0; n < 4; ++n)
                acc[m][n] = 0.0f;

        for (int kt = 0; kt < DDIM / BK; ++kt) {
            const int k0 = kt * BK;
            #pragma unroll
            for (int i = 0; i < 4; ++i) {
                int c = tid + i * 512;
                int r = c >> 3, g = c & 7;
                int gs = (g ^ (r & 7)) * 8;
                gload16(Xb + (size_t)(row0 + r) * DDIM + k0 + gs, Ab + c * 8);
            }
            #pragma unroll
            for (int i = 0; i < 2; ++i) {
                int c = tid + i * 512;
                int r = c >> 3, g = c & 7;
                int gs = (g ^ (r & 7)) * 8;
                gload16(Eb + (size_t)(v0 + r) * DDIM + k0 + gs, Bb + c * 8);
            }
            __syncthreads();
            #pragma unroll
            for (int ks = 0; ks < 2; ++ks) {
                bf16x8 av[4], bv[4];
                #pragma unroll
                for (int m = 0; m < 4; ++m) {
                    int r  = wm * 64 + m * 16 + l15;
                    int ke = (ks * 32 + lhi * 8) ^ ((r & 7) << 3);
                    av[m] = *(const bf16x8*)(Ab + r * BK + ke);
                }
                #pragma unroll
                for (int n = 0; n < 4; ++n) {
                    int c  = wn * 64 + n * 16 + l15;
                    int ke = (ks * 32 + lhi * 8) ^ ((c & 7) << 3);
                    bv[n] = *(const bf16x8*)(Bb + c * BK + ke);
                }
                #pragma unroll
                for (int m = 0; m < 4; ++m)
                    #pragma unroll
                    for (int n = 0; n < 4; ++n)
                        acc[m][n] = __builtin_amdgcn_mfma_f32_16x16x32_bf16(
                            av[m], bv[n], acc[m][n], 0, 0, 0);
            }
            __syncthreads();
        }

        float inv[4];
        #pragma unroll
        for (int n = 0; n < 4; ++n) inv[n] = invn[v0 + wn * 64 + n * 16 + l15];
        #pragma unroll
        for (int m = 0; m < 4; ++m) {
            #pragma unroll
            for (int j = 0; j < 4; ++j) {
                float v = fmaxf(fmaxf(acc[m][0][j] * inv[0], acc[m][1][j] * inv[1]),
                                fmaxf(acc[m][2][j] * inv[2], acc[m][3][j] * inv[3]));
                #pragma unroll
                for (int off = 1; off < 16; off <<= 1)
                    v = fmaxf(v, __shfl_xor(v, off, 64));
                if (l15 == 0) {
                    int row = row0 + wm * 64 + m * 16 + lhi * 4 + j;
                    tm[(size_t)row * TW + t * 2 + wn] = v;
                }
            }
        }
    }
}

__global__ void k_select1(const float* __restrict__ tm,
                          unsigned* __restrict__ list, unsigned* __restrict__ cnt,
                          unsigned long long* __restrict__ keys) {
    constexpr int TW = NT * 2;
    int row  = blockIdx.x * 4 + (threadIdx.x >> 6);
    int lane = threadIdx.x & 63;
    if (lane == 0) keys[row] = 0ull;
    const float* p = tm + (size_t)row * TW;
    float m = -INFINITY;
    for (int i = lane; i < TW; i += 64) m = fmaxf(m, p[i]);
    #pragma unroll
    for (int off = 32; off; off >>= 1) m = fmaxf(m, __shfl_xor(m, off, 64));
    float th = m - TAU1;
    for (int i = lane; i < TW; i += 64) {
        if (p[i] >= th) {
            unsigned slot = atomicAdd(cnt, 1u);
            if (slot < LISTCAP) list[slot] = ((unsigned)row << 14) | (unsigned)i;
        }
    }
}

__global__ __launch_bounds__(256)
void k_rescore64(const float* __restrict__ X, const float* __restrict__ E,
                 const float* __restrict__ invn,
                 const unsigned* __restrict__ list, const unsigned* __restrict__ cnt,
                 unsigned long long* __restrict__ keys) {
    unsigned n = *cnt; if (n > LISTCAP) n = LISTCAP;
    for (unsigned ci = blockIdx.x; ci < n; ci += gridDim.x) {
        unsigned e = list[ci];
        int row = (int)(e >> 14);
        int idx = (int)(e & 16383u);
        int v0  = (idx >> 1) * BN + (idx & 1) * 64;
        int col  = v0 + ((int)threadIdx.x >> 2);
        int part = (int)threadIdx.x & 3;
        if (col < VOCAB) {
            const float4* xp = (const float4*)(X + (size_t)row * DDIM + part * 128);
            const float4* ep = (const float4*)(E + (size_t)col * DDIM + part * 128);
            double s = 0.0;
            #pragma unroll 8
            for (int d = 0; d < 32; ++d) {
                float4 a = xp[d], b = ep[d];
                s = fma((double)a.x, (double)b.x, s);
                s = fma((double)a.y, (double)b.y, s);
                s = fma((double)a.z, (double)b.z, s);
                s = fma((double)a.w, (double)b.w, s);
            }
            s += __shfl_xor(s, 1, 64);
            s += __shfl_xor(s, 2, 64);
            if (part == 0) {
                float fs = (float)(s * (double)invn[col]);
                unsigned long long key = ((unsigned long long)enc_f32(fs) << 32)
                                       | (unsigned long long)(0xffffffffu - (unsigned)col);
                atomicMax(keys + row, key);
            }
        }
    }
}

// ===================== fallback path (round-1, verified) =====================

#define BM 128
#define VC 33

__global__ void k_init_fb(unsigned int* rowmax, unsigned long long* keys) {
    int i = blockIdx.x * 256 + threadIdx.x;
    if (i < NROWS) { rowmax[i] = 0u; keys[i] = 0ull; }
}

__global__ void k_enorm(const float* __restrict__ E, float* __restrict__ invn) {
    int lane = threadIdx.x & 63;
    int wid  = blockIdx.x * 4 + (threadIdx.x >> 6);
    int nw   = gridDim.x * 4;
    for (int r = wid; r < VOCAB; r += nw) {
        const float4* p = (const float4*)(E + (size_t)r * DDIM);
        float4 a = p[lane];
        float4 b = p[lane + 64];
        float s = a.x*a.x + a.y*a.y + a.z*a.z + a.w*a.w
                + b.x*b.x + b.y*b.y + b.z*b.z + b.w*b.w;
        #pragma unroll
        for (int off = 32; off; off >>= 1) s += __shfl_xor(s, off, 64);
        if (lane == 0) invn[r] = 1.0f / fmaxf(sqrtf(s), 1e-12f);
    }
}

__device__ __noinline__ void rescore1(const float* __restrict__ X,
                                      const float* __restrict__ E,
                                      float iv, int row, int col,
                                      unsigned long long* keys) {
    const float4* xp = (const float4*)(X + (size_t)row * DDIM);
    const float4* ep = (const float4*)(E + (size_t)col * DDIM);
    double a0 = 0.0, a1 = 0.0, a2 = 0.0, a3 = 0.0;
    for (int d = 0; d < DDIM / 4; ++d) {
        float4 x4 = xp[d], e4 = ep[d];
        a0 = fma((double)x4.x, (double)e4.x, a0);
        a1 = fma((double)x4.y, (double)e4.y, a1);
        a2 = fma((double)x4.z, (double)e4.z, a2);
        a3 = fma((double)x4.w, (double)e4.w, a3);
    }
    float fs = (float)((((a0 + a1) + (a2 + a3))) * (double)iv);
    unsigned long long key = ((unsigned long long)enc_f32(fs) << 32)
                           | (unsigned long long)(0xffffffffu - (unsigned int)col);
    atomicMax(keys + row, key);
}

template <int PASS>
__global__ __launch_bounds__(256, 2)
void k_gemm_fb(const float* __restrict__ X, const float* __restrict__ E,
               const float* __restrict__ invn,
               unsigned int* __restrict__ rowmax,
               unsigned long long* __restrict__ keys)
{
    __shared__ __align__(16) short Abuf[BM * BK];
    __shared__ __align__(16) short Bbuf[BN * BK];

    const int tid  = threadIdx.x;
    const int lane = tid & 63;
    const int w    = tid >> 6;
    const int wm   = w >> 1, wn = w & 1;
    const int row0 = blockIdx.y * BM;
    const int l15  = lane & 15, lhi = lane >> 4;

    float rmax[4][4];
    float thr[4][4];
    #pragma unroll
    for (int m = 0; m < 4; ++m)
        #pragma unroll
        for (int j = 0; j < 4; ++j) {
            rmax[m][j] = -INFINITY;
            if (PASS == 2) {
                int row = row0 + wm * 64 + m * 16 + lhi * 4 + j;
                thr[m][j] = dec_f32(rowmax[row]) - TAU1;
            }
        }

    for (int t = blockIdx.x; t < NT; t += VC) {
        const int v0 = t * BN;
        f32x4 acc[4][4];
        #pragma unroll
        for (int m = 0; m < 4; ++m)
            #pragma unroll
            for (int n = 0; n < 4; ++n)
                acc[m][n] = 0.0f;

        for (int kt = 0; kt < DDIM / BK; ++kt) {
            const int k0 = kt * BK;
            #pragma unroll
            for (int i = 0; i < 4; ++i) {
                int f  = tid + i * 256;
                int r  = f >> 3;
                int ks = (f & 7) * 8;
                const float* src = X + (size_t)(row0 + r) * DDIM + k0 + ks;
                float4 aa = *(const float4*)src;
                float4 bb = *(const float4*)(src + 4);
                *(uint4*)(Abuf + r * BK + (ks ^ ((r & 7) << 3))) = pack8(aa, bb);
            }
            #pragma unroll
            for (int i = 0; i < 4; ++i) {
                int f  = tid + i * 256;
                int r  = f >> 3;
                int ks = (f & 7) * 8;
                float4 aa = {0.f,0.f,0.f,0.f}, bb = {0.f,0.f,0.f,0.f};
                if (v0 + r < VOCAB) {
                    const float* src = E + (size_t)(v0 + r) * DDIM + k0 + ks;
                    aa = *(const float4*)src;
                    bb = *(const float4*)(src + 4);
                }
                *(uint4*)(Bbuf + r * BK + (ks ^ ((r & 7) << 3))) = pack8(aa, bb);
            }
            __syncthreads();
            #pragma unroll
            for (int ks = 0; ks < 2; ++ks) {
                bf16x8 av[4], bv[4];
                #pragma unroll
                for (int m = 0; m < 4; ++m) {
                    int r  = wm * 64 + m * 16 + l15;
                    int ke = (ks * 32 + lhi * 8) ^ ((r & 7) << 3);
                    av[m] = *(const bf16x8*)(Abuf + r * BK + ke);
                }
                #pragma unroll
                for (int n = 0; n < 4; ++n) {
                    int c  = wn * 64 + n * 16 + l15;
                    int ke = (ks * 32 + lhi * 8) ^ ((c & 7) << 3);
                    bv[n] = *(const bf16x8*)(Bbuf + c * BK + ke);
                }
                #pragma unroll
                for (int m = 0; m < 4; ++m)
                    #pragma unroll
                    for (int n = 0; n < 4; ++n)
                        acc[m][n] = __builtin_amdgcn_mfma_f32_16x16x32_bf16(
                            av[m], bv[n], acc[m][n], 0, 0, 0);
            }
            __syncthreads();
        }

        float inv[4]; int colv[4];
        #pragma unroll
        for (int n = 0; n < 4; ++n) {
            int c = v0 + wn * 64 + n * 16 + l15;
            colv[n] = c;
            inv[n] = (c < VOCAB) ? invn[c] : 0.0f;
        }
        if (PASS == 1) {
            #pragma unroll
            for (int m = 0; m < 4; ++m)
                #pragma unroll
                for (int n = 0; n < 4; ++n)
                    if (colv[n] < VOCAB) {
                        #pragma unroll
                        for (int j = 0; j < 4; ++j)
                            rmax[m][j] = fmaxf(rmax[m][j], acc[m][n][j] * inv[n]);
                    }
        } else {
            #pragma unroll
            for (int m = 0; m < 4; ++m)
                #pragma unroll
                for (int n = 0; n < 4; ++n)
                    if (colv[n] < VOCAB) {
                        #pragma unroll
                        for (int j = 0; j < 4; ++j) {
                            float sc = acc[m][n][j] * inv[n];
                            if (sc >= thr[m][j]) {
                                int row = row0 + wm * 64 + m * 16 + lhi * 4 + j;
                                rescore1(X, E, inv[n], row, colv[n], keys);
                            }
                        }
                    }
        }
    }

    if (PASS == 1) {
        #pragma unroll
        for (int m = 0; m < 4; ++m)
            #pragma unroll
            for (int j = 0; j < 4; ++j) {
                float v = rmax[m][j];
                #pragma unroll
                for (int off = 1; off < 16; off <<= 1)
                    v = fmaxf(v, __shfl_xor(v, off, 64));
                if (l15 == 0) {
                    int row = row0 + wm * 64 + m * 16 + lhi * 4 + j;
                    atomicMax(rowmax + row, enc_f32(v));
                }
            }
    }
}

// =============================== launch ===============================

extern "C" void kernel_launch(void* const* d_in, const int* in_sizes, int n_in,
                              void* d_out, int out_size, void* d_ws, size_t ws_size,
                              hipStream_t stream) {
    const float* X = (const float*)d_in[0];   // (4096, 512)
    const float* E = (const float*)d_in[1];   // (50257, 512)
    int* out = (int*)d_out;                   // (4096,) int32
    char* ws = (char*)d_ws;

    const size_t sz_Eb    = (size_t)EB_ROWS * DDIM * 2;          // 51,511,296
    const size_t sz_Xb    = (size_t)NROWS * DDIM * 2;            //  4,194,304
    const size_t sz_invn  = (size_t)EB_ROWS * 4;                 //    201,216
    const size_t sz_keys  = (size_t)NROWS * 8;
    const size_t sz_list  = (size_t)LISTCAP * 4;
    const size_t fixed    = sz_Eb + sz_Xb + sz_invn + sz_keys + sz_list + 256;
    const size_t sz_tm16  = (size_t)NROWS * TW16 * 2;            // 103,022,592
    const size_t sz_tm1   = (size_t)NROWS * (NT * 2) * 4;        // 12,877,824

    int tier = 0;
    if (ws_size >= fixed + sz_tm16)     tier = 16;
    else if (ws_size >= fixed + sz_tm1) tier = 1;

    if (tier) {
        const size_t sz_tm = (tier == 16) ? sz_tm16 : sz_tm1;
        short* Eb   = (short*)(ws);
        short* Xb   = (short*)(ws + sz_Eb);
        float* invn = (float*)(ws + sz_Eb + sz_Xb);
        char*  tmb  = ws + sz_Eb + sz_Xb + sz_invn;
        unsigned long long* keys = (unsigned long long*)(tmb + sz_tm);
        unsigned* list = (unsigned*)((char*)keys + sz_keys);
        unsigned* cnt  = (unsigned*)((char*)list + sz_list);

        k_conv_x<<<(NROWS * DDIM / 8) / 256, 256, 0, stream>>>(X, Xb, cnt);
        k_conv_e<<<2048, 256, 0, stream>>>(E, Eb, invn);
        dim3 g(RB2, VC2);
        if (tier == 16) {
            const size_t smem = (size_t)3 * (BM2 * BK + BN * BK) * sizeof(short); // 144 KB
            k_gemm_fast16<<<g, 512, smem, stream>>>(Xb, Eb, invn, (unsigned short*)tmb);
            k_select16<<<NROWS / 4, 256, 0, stream>>>((unsigned short*)tmb, list, cnt, keys);
            k_rescore4<<<2048, 256, 0, stream>>>(X, E, invn, list, cnt, keys);
        } else {
            k_gemm_fast1<<<g, 512, 0, stream>>>(Xb, Eb, invn, (float*)tmb);
            k_select1<<<NROWS / 4, 256, 0, stream>>>((float*)tmb, list, cnt, keys);
            k_rescore64<<<2048, 256, 0, stream>>>(X, E, invn, list, cnt, keys);
        }
        k_final<<<(NROWS + 255) / 256, 256, 0, stream>>>(keys, out);
    } else {
        // fallback: round-1 verified two-pass path (small ws)
        float* invn = (float*)ws;
        size_t off0 = ((size_t)VOCAB * 4 + 255) & ~(size_t)255;
        unsigned int* rowmax = (unsigned int*)(ws + off0);
        size_t off1 = off0 + (((size_t)NROWS * 4 + 255) & ~(size_t)255);
        unsigned long long* keys = (unsigned long long*)(ws + off1);

        k_init_fb<<<(NROWS + 255) / 256, 256, 0, stream>>>(rowmax, keys);
        k_enorm<<<1024, 256, 0, stream>>>(E, invn);
        dim3 g(VC, NROWS / BM);
        k_gemm_fb<1><<<g, 256, 0, stream>>>(X, E, invn, rowmax, keys);
        k_gemm_fb<2><<<g, 256, 0, stream>>>(X, E, invn, rowmax, keys);
        k_final<<<(NROWS + 255) / 256, 256, 0, stream>>>(keys, out);
    }
}